// Round 15
// baseline (364.592 us; speedup 1.0000x reference)
//
#include <hip/hip_runtime.h>
#include <hip/hip_bf16.h>

#define SDIM 128
#define NCOL 16384          // SDIM*SDIM
#define ROWS_TOTAL 4096     // 4*1024

using bf16x8 = __attribute__((ext_vector_type(8))) __bf16;
using su8    = __attribute__((ext_vector_type(8))) ushort;
using f32x4  = __attribute__((ext_vector_type(4))) float;

// f32 -> bf16 (RNE) via the HW cast
__device__ __forceinline__ ushort f2bf(float f) {
  __hip_bfloat16 h = __float2bfloat16(f);
  union { __hip_bfloat16 h; ushort u; } c; c.h = h;
  return c.u;
}

// ---- prep: L,R f32 -> bf16 in fragment-major layout ----
// out[(((t1*4+ks)*8+tb)*4+g)*16+tl][8] = in[t1][tb*16+tl][ks*32+g*8 + 0..8)
__global__ __launch_bounds__(256) void k_prep(const float* __restrict__ L,
                                              const float* __restrict__ R,
                                              ushort* __restrict__ Lt,
                                              ushort* __restrict__ Rt) {
  int id = blockIdx.x * 256 + threadIdx.x;    // 0 .. 524287
  const float* in = (id < 262144) ? L : R;
  ushort* outp    = (id < 262144) ? Lt : Rt;
  int t  = id & 262143;
  int t1 = t >> 11;
  int ks = (t >> 9) & 3;
  int tb = (t >> 6) & 7;
  int g  = (t >> 4) & 3;
  int tl = t & 15;
  const float* src = in + (size_t)(t1 * 128 + tb * 16 + tl) * 128 + ks * 32 + g * 8;
  float4 a = *reinterpret_cast<const float4*>(src);
  float4 b = *reinterpret_cast<const float4*>(src + 4);
  su8 o;
  o[0] = f2bf(a.x); o[1] = f2bf(a.y); o[2] = f2bf(a.z); o[3] = f2bf(a.w);
  o[4] = f2bf(b.x); o[5] = f2bf(b.y); o[6] = f2bf(b.z); o[7] = f2bf(b.w);
  *reinterpret_cast<su8*>(outp + (size_t)t * 8) = o;
}

// ---- stage 1: T3 = sum_k L[m][j][k] * x[r][k*128+m], fragment-major output ----
// grid = rowtiles*16, 256 thr. block: 16 rows x 8 m's (mg). LDS 32 KB, one barrier.
// IDENTITY mapping: XCD = bid%8 = mg%8 -> each XCD touches only 2 Lt m-slices
// (512 KB, L2-resident); the 64 rt-blocks sharing an mg re-read Lt from L2 not L3.
__global__ __launch_bounds__(256, 4) void k_stage1(const float* __restrict__ x,
                                                   const ushort* __restrict__ Lt,
                                                   ushort* __restrict__ T3,
                                                   int rowtiles) {
  unsigned bid = blockIdx.x;
  int rt = bid >> 4;
  int mg = bid & 15;
  int row0 = rt * 16;
  int m0 = mg * 8;

  __shared__ __align__(16) ushort xs[16384];  // [m 8][r 16][k 128], XOR-swizzled on r

  int tid = threadIdx.x;
  // ---- stage x slice into LDS (transpose m<->(r,k), f32->bf16) ----
  for (int t2 = 0; t2 < 2; ++t2) {
    int task = t2 * 256 + tid;                // 512 tasks
    int r = task >> 5, kq = task & 31;
    int k = kq << 2;
    const float4* p4 = reinterpret_cast<const float4*>(
        x + (size_t)(row0 + r) * NCOL + (size_t)k * SDIM + m0);
    ushort vv[4][8];
#pragma unroll
    for (int kk = 0; kk < 4; ++kk) {
      float4 a0 = p4[kk * 32 + 0];
      float4 a1 = p4[kk * 32 + 1];
      vv[kk][0] = f2bf(a0.x); vv[kk][1] = f2bf(a0.y);
      vv[kk][2] = f2bf(a0.z); vv[kk][3] = f2bf(a0.w);
      vv[kk][4] = f2bf(a1.x); vv[kk][5] = f2bf(a1.y);
      vv[kk][6] = f2bf(a1.z); vv[kk][7] = f2bf(a1.w);
    }
#pragma unroll
    for (int mm = 0; mm < 8; ++mm) {
      int e = ((mm * 16 + r) << 7) + k;
      int idx = e ^ ((r & 7) << 3);
      ushort4 w; w.x = vv[0][mm]; w.y = vv[1][mm]; w.z = vv[2][mm]; w.w = vv[3][mm];
      *reinterpret_cast<ushort4*>(&xs[idx]) = w;
    }
  }
  __syncthreads();

  int wave = tid >> 6, lane = tid & 63;
  int l15 = lane & 15, g = lane >> 4;
  int swz = (l15 & 7) << 3;

  const ushort* Lp = Lt + ((size_t)m0 * 32 + (size_t)wave * 2) * 512 + (size_t)lane * 8;

  f32x4 st[2][8];   // [jt][m], static indices via full unroll

#pragma unroll
  for (int m = 0; m < 8; ++m) {
    // ---- A-operand: X^T fragments from LDS ----
    bf16x8 xf[4];
#pragma unroll
    for (int ks = 0; ks < 4; ++ks) {
      int e = ((m * 16 + l15) << 7) + ks * 32 + g * 8;
      xf[ks] = *reinterpret_cast<const bf16x8*>(&xs[e ^ swz]);
    }
    f32x4 a0 = {0.f, 0.f, 0.f, 0.f};
    f32x4 a1 = {0.f, 0.f, 0.f, 0.f};
#pragma unroll
    for (int ks = 0; ks < 4; ++ks) {
      bf16x8 l0 = *reinterpret_cast<const bf16x8*>(Lp + (size_t)((m * 4 + ks) * 8 + 0) * 512);
      bf16x8 l1 = *reinterpret_cast<const bf16x8*>(Lp + (size_t)((m * 4 + ks) * 8 + 1) * 512);
      a0 = __builtin_amdgcn_mfma_f32_16x16x32_bf16(xf[ks], l0, a0, 0, 0, 0);
      a1 = __builtin_amdgcn_mfma_f32_16x16x32_bf16(xf[ks], l1, a1, 0, 0, 0);
    }
    st[0][m] = a0;
    st[1][m] = a1;
  }

  // ---- epilogue: D[row=rr=g*4+v][col=j]; write fragment-major T3 runs ----
  int ks1 = mg >> 2, g2 = mg & 3;
#pragma unroll
  for (int jt = 0; jt < 2; ++jt) {
    int j = wave * 32 + jt * 16 + l15;
#pragma unroll
    for (int v = 0; v < 4; ++v) {
      int rr = g * 4 + v;
      su8 o;
      o[0] = f2bf(st[jt][0][v]); o[1] = f2bf(st[jt][1][v]);
      o[2] = f2bf(st[jt][2][v]); o[3] = f2bf(st[jt][3][v]);
      o[4] = f2bf(st[jt][4][v]); o[5] = f2bf(st[jt][5][v]);
      o[6] = f2bf(st[jt][6][v]); o[7] = f2bf(st[jt][7][v]);
      size_t a = (((size_t)(rt * 128 + j) * 4 + ks1) * 64 + g2 * 16 + rr) * 8;
      *reinterpret_cast<su8*>(T3 + a) = o;
    }
  }
}

// ---- stage 2: out[r][i*128+j] = sum_m R[j][i][m] * T[r][m][j] ----
// grid = rowtiles*8, 512 thr = 8 waves = all 128 i (no duplication anywhere).
// The block's T3 slice (64 KB, CONTIGUOUS in fragment-major layout) is staged
// into LDS once and ds_read by all 8 waves. bf (R) streams from the jg-pinned
// XCD's L2 (512 KB slice; XCD = bid%8 = jg).
__global__ __launch_bounds__(512, 4) void k_stage2(const ushort* __restrict__ T3,
                                                   const ushort* __restrict__ Rt,
                                                   float* __restrict__ out,
                                                   int rowtiles) {
  unsigned bid = blockIdx.x;              // grid = rowtiles*8
  int jg = bid & 7;                       // pinned: one j-group per XCD
  int rt = bid >> 3;
  int row0 = rt * 16;
  int j0 = jg * 16;

  __shared__ __align__(16) ushort ts[32768];   // 64 KB linear copy of T3 slice

  int tid = threadIdx.x;                  // 0..511
  int wave = tid >> 6, lane = tid & 63;
  int l15 = lane & 15, g = lane >> 4;
  int ibase = wave * 16;

  // ---- stage af slice into LDS: 64 KB contiguous, 512 thr x 8 x 16B ----
  {
    const su8* s8 = reinterpret_cast<const su8*>(T3 + (size_t)(rt * 128 + j0) * 4 * 512);
    su8* d8 = reinterpret_cast<su8*>(ts);
#pragma unroll
    for (int q = 0; q < 8; ++q)
      d8[q * 512 + tid] = s8[q * 512 + tid];
  }
  __syncthreads();

  f32x4 acc[16];
#pragma unroll
  for (int jj = 0; jj < 16; ++jj) acc[jj] = {0.f, 0.f, 0.f, 0.f};

  const ushort* Rp = Rt + ((size_t)j0 * 32 + wave) * 512 + (size_t)lane * 8;
  const ushort* tp = ts + (size_t)lane * 8;

#pragma unroll
  for (int jj = 0; jj < 16; ++jj) {
#pragma unroll
    for (int ks = 0; ks < 4; ++ks) {
      bf16x8 af = *reinterpret_cast<const bf16x8*>(tp + (size_t)(jj * 4 + ks) * 512);
      bf16x8 bf = *reinterpret_cast<const bf16x8*>(Rp + (size_t)(jj * 32 + ks * 8) * 512);
      acc[jj] = __builtin_amdgcn_mfma_f32_16x16x32_bf16(af, bf, acc[jj], 0, 0, 0);
    }
  }

  // ---- epilogue: each lane owns full 64B out lines, written back-to-back ----
#pragma unroll
  for (int v = 0; v < 4; ++v) {
    float* dst = out + (size_t)(row0 + g * 4 + v) * NCOL + (size_t)(ibase + l15) * SDIM + j0;
#pragma unroll
    for (int q = 0; q < 4; ++q) {
      float4 o; o.x = acc[q * 4 + 0][v]; o.y = acc[q * 4 + 1][v];
                o.z = acc[q * 4 + 2][v]; o.w = acc[q * 4 + 3][v];
      *reinterpret_cast<float4*>(dst + q * 4) = o;
    }
  }
}

extern "C" void kernel_launch(void* const* d_in, const int* in_sizes, int n_in,
                              void* d_out, int out_size, void* d_ws, size_t ws_size,
                              hipStream_t stream) {
  const float* x = (const float*)d_in[0];
  const float* L = (const float*)d_in[1];
  const float* R = (const float*)d_in[2];
  float* out = (float*)d_out;

  ushort* Lt = (ushort*)d_ws;
  ushort* Rt = Lt + 2097152;
  ushort* T3 = Rt + 2097152;
  const size_t lr_bytes = (size_t)2 * 2097152 * 2;
  size_t avail = ws_size > lr_bytes ? ws_size - lr_bytes : 0;
  // Chunk rows so the T3 round-trip stays L3-resident (chunk working set:
  // x 64MB + T3 32MB + out 64MB = 160MB < 256MB Infinity Cache).
  long long rpc = 1024;
  long long fit = (long long)(avail / ((size_t)NCOL * 2));
  if (rpc > fit) rpc = fit;
  if (rpc > ROWS_TOTAL) rpc = ROWS_TOTAL;
  rpc &= ~15LL;
  if (rpc < 16) rpc = 16;

  k_prep<<<2048, 256, 0, stream>>>(L, R, Lt, Rt);

  for (long long row0 = 0; row0 < ROWS_TOTAL; row0 += rpc) {
    long long rows = (ROWS_TOTAL - row0 < rpc) ? (ROWS_TOTAL - row0) : rpc;
    int rowtiles = (int)(rows / 16);
    k_stage1<<<dim3(rowtiles * 16), 256, 0, stream>>>(x + row0 * NCOL, Lt, T3, rowtiles);
    k_stage2<<<dim3(rowtiles * 8), 512, 0, stream>>>(T3, Rt, out + row0 * NCOL, rowtiles);
  }
}

// Round 16
// 326.339 us; speedup vs baseline: 1.1172x; 1.1172x over previous
//
#include <hip/hip_runtime.h>
#include <hip/hip_bf16.h>

#define SDIM 128
#define NCOL 16384          // SDIM*SDIM
#define ROWS_TOTAL 4096     // 4*1024

using bf16x8 = __attribute__((ext_vector_type(8))) __bf16;
using su8    = __attribute__((ext_vector_type(8))) ushort;
using f32x4  = __attribute__((ext_vector_type(4))) float;

// f32 -> bf16 (RNE) via the HW cast
__device__ __forceinline__ ushort f2bf(float f) {
  __hip_bfloat16 h = __float2bfloat16(f);
  union { __hip_bfloat16 h; ushort u; } c; c.h = h;
  return c.u;
}

// ---- prep: L,R f32 -> bf16 in fragment-major layout ----
// out[(((t1*4+ks)*8+tb)*4+g)*16+tl][8] = in[t1][tb*16+tl][ks*32+g*8 + 0..8)
__global__ __launch_bounds__(256) void k_prep(const float* __restrict__ L,
                                              const float* __restrict__ R,
                                              ushort* __restrict__ Lt,
                                              ushort* __restrict__ Rt) {
  int id = blockIdx.x * 256 + threadIdx.x;    // 0 .. 524287
  const float* in = (id < 262144) ? L : R;
  ushort* outp    = (id < 262144) ? Lt : Rt;
  int t  = id & 262143;
  int t1 = t >> 11;
  int ks = (t >> 9) & 3;
  int tb = (t >> 6) & 7;
  int g  = (t >> 4) & 3;
  int tl = t & 15;
  const float* src = in + (size_t)(t1 * 128 + tb * 16 + tl) * 128 + ks * 32 + g * 8;
  float4 a = *reinterpret_cast<const float4*>(src);
  float4 b = *reinterpret_cast<const float4*>(src + 4);
  su8 o;
  o[0] = f2bf(a.x); o[1] = f2bf(a.y); o[2] = f2bf(a.z); o[3] = f2bf(a.w);
  o[4] = f2bf(b.x); o[5] = f2bf(b.y); o[6] = f2bf(b.z); o[7] = f2bf(b.w);
  *reinterpret_cast<su8*>(outp + (size_t)t * 8) = o;
}

// ---- stage 1: T3 = sum_k L[m][j][k] * x[r][k*128+m], fragment-major output ----
// grid = rowtiles*16, 256 thr. block: 16 rows x 8 m's (mg). LDS 32 KB, one barrier.
// Mapping XCD = mg>>1: mg pair (2c,2c+1) colocated on XCD c (adjacent pos) so
// every 64B x line (spans m 0..15 = one mg pair) is fetched by ONE XCD once,
// AND each XCD touches only 2 Lt slices = 512 KB -> L2-resident.
__global__ __launch_bounds__(256, 4) void k_stage1(const float* __restrict__ x,
                                                   const ushort* __restrict__ Lt,
                                                   ushort* __restrict__ T3,
                                                   int rowtiles) {
  unsigned bid = blockIdx.x;
  int c   = bid & 7;                 // XCD
  int pos = bid >> 3;
  int mg  = c * 2 + (pos & 1);
  int rt  = pos >> 1;
  int row0 = rt * 16;
  int m0 = mg * 8;

  __shared__ __align__(16) ushort xs[16384];  // [m 8][r 16][k 128], XOR-swizzled on r

  int tid = threadIdx.x;
  // ---- stage x slice into LDS (transpose m<->(r,k), f32->bf16) ----
  for (int t2 = 0; t2 < 2; ++t2) {
    int task = t2 * 256 + tid;                // 512 tasks
    int r = task >> 5, kq = task & 31;
    int k = kq << 2;
    const float4* p4 = reinterpret_cast<const float4*>(
        x + (size_t)(row0 + r) * NCOL + (size_t)k * SDIM + m0);
    ushort vv[4][8];
#pragma unroll
    for (int kk = 0; kk < 4; ++kk) {
      float4 a0 = p4[kk * 32 + 0];
      float4 a1 = p4[kk * 32 + 1];
      vv[kk][0] = f2bf(a0.x); vv[kk][1] = f2bf(a0.y);
      vv[kk][2] = f2bf(a0.z); vv[kk][3] = f2bf(a0.w);
      vv[kk][4] = f2bf(a1.x); vv[kk][5] = f2bf(a1.y);
      vv[kk][6] = f2bf(a1.z); vv[kk][7] = f2bf(a1.w);
    }
#pragma unroll
    for (int mm = 0; mm < 8; ++mm) {
      int e = ((mm * 16 + r) << 7) + k;
      int idx = e ^ ((r & 7) << 3);
      ushort4 w; w.x = vv[0][mm]; w.y = vv[1][mm]; w.z = vv[2][mm]; w.w = vv[3][mm];
      *reinterpret_cast<ushort4*>(&xs[idx]) = w;
    }
  }
  __syncthreads();

  int wave = tid >> 6, lane = tid & 63;
  int l15 = lane & 15, g = lane >> 4;
  int swz = (l15 & 7) << 3;

  const ushort* Lp = Lt + ((size_t)m0 * 32 + (size_t)wave * 2) * 512 + (size_t)lane * 8;

  f32x4 st[2][8];   // [jt][m], static indices via full unroll

#pragma unroll
  for (int m = 0; m < 8; ++m) {
    // ---- A-operand: X^T fragments from LDS ----
    bf16x8 xf[4];
#pragma unroll
    for (int ks = 0; ks < 4; ++ks) {
      int e = ((m * 16 + l15) << 7) + ks * 32 + g * 8;
      xf[ks] = *reinterpret_cast<const bf16x8*>(&xs[e ^ swz]);
    }
    f32x4 a0 = {0.f, 0.f, 0.f, 0.f};
    f32x4 a1 = {0.f, 0.f, 0.f, 0.f};
#pragma unroll
    for (int ks = 0; ks < 4; ++ks) {
      bf16x8 l0 = *reinterpret_cast<const bf16x8*>(Lp + (size_t)((m * 4 + ks) * 8 + 0) * 512);
      bf16x8 l1 = *reinterpret_cast<const bf16x8*>(Lp + (size_t)((m * 4 + ks) * 8 + 1) * 512);
      a0 = __builtin_amdgcn_mfma_f32_16x16x32_bf16(xf[ks], l0, a0, 0, 0, 0);
      a1 = __builtin_amdgcn_mfma_f32_16x16x32_bf16(xf[ks], l1, a1, 0, 0, 0);
    }
    st[0][m] = a0;
    st[1][m] = a1;
  }

  // ---- epilogue: D[row=rr=g*4+v][col=j]; write fragment-major T3 runs ----
  int ks1 = mg >> 2, g2 = mg & 3;
#pragma unroll
  for (int jt = 0; jt < 2; ++jt) {
    int j = wave * 32 + jt * 16 + l15;
#pragma unroll
    for (int v = 0; v < 4; ++v) {
      int rr = g * 4 + v;
      su8 o;
      o[0] = f2bf(st[jt][0][v]); o[1] = f2bf(st[jt][1][v]);
      o[2] = f2bf(st[jt][2][v]); o[3] = f2bf(st[jt][3][v]);
      o[4] = f2bf(st[jt][4][v]); o[5] = f2bf(st[jt][5][v]);
      o[6] = f2bf(st[jt][6][v]); o[7] = f2bf(st[jt][7][v]);
      size_t a = (((size_t)(rt * 128 + j) * 4 + ks1) * 64 + g2 * 16 + rr) * 8;
      *reinterpret_cast<su8*>(T3 + a) = o;
    }
  }
}

// ---- stage 2: out[r][i*128+j] = sum_m R[j][i][m] * T[r][m][j] ----
// grid = rowtiles*8, 512 thr = 8 waves = all 128 i (no duplication anywhere).
// The block's T3 slice (64 KB, CONTIGUOUS in fragment-major layout) is staged
// into LDS once and ds_read by all 8 waves. bf (R) streams from the jg-pinned
// XCD's L2 (512 KB slice; XCD = bid%8 = jg).
__global__ __launch_bounds__(512, 4) void k_stage2(const ushort* __restrict__ T3,
                                                   const ushort* __restrict__ Rt,
                                                   float* __restrict__ out,
                                                   int rowtiles) {
  unsigned bid = blockIdx.x;              // grid = rowtiles*8
  int jg = bid & 7;                       // pinned: one j-group per XCD
  int rt = bid >> 3;
  int row0 = rt * 16;
  int j0 = jg * 16;

  __shared__ __align__(16) ushort ts[32768];   // 64 KB linear copy of T3 slice

  int tid = threadIdx.x;                  // 0..511
  int wave = tid >> 6, lane = tid & 63;
  int l15 = lane & 15, g = lane >> 4;
  int ibase = wave * 16;

  // ---- stage af slice into LDS: 64 KB contiguous, 512 thr x 8 x 16B ----
  {
    const su8* s8 = reinterpret_cast<const su8*>(T3 + (size_t)(rt * 128 + j0) * 4 * 512);
    su8* d8 = reinterpret_cast<su8*>(ts);
#pragma unroll
    for (int q = 0; q < 8; ++q)
      d8[q * 512 + tid] = s8[q * 512 + tid];
  }
  __syncthreads();

  f32x4 acc[16];
#pragma unroll
  for (int jj = 0; jj < 16; ++jj) acc[jj] = {0.f, 0.f, 0.f, 0.f};

  const ushort* Rp = Rt + ((size_t)j0 * 32 + wave) * 512 + (size_t)lane * 8;
  const ushort* tp = ts + (size_t)lane * 8;

#pragma unroll
  for (int jj = 0; jj < 16; ++jj) {
#pragma unroll
    for (int ks = 0; ks < 4; ++ks) {
      bf16x8 af = *reinterpret_cast<const bf16x8*>(tp + (size_t)(jj * 4 + ks) * 512);
      bf16x8 bf = *reinterpret_cast<const bf16x8*>(Rp + (size_t)(jj * 32 + ks * 8) * 512);
      acc[jj] = __builtin_amdgcn_mfma_f32_16x16x32_bf16(af, bf, acc[jj], 0, 0, 0);
    }
  }

  // ---- epilogue: each lane owns full 64B out lines, written back-to-back ----
#pragma unroll
  for (int v = 0; v < 4; ++v) {
    float* dst = out + (size_t)(row0 + g * 4 + v) * NCOL + (size_t)(ibase + l15) * SDIM + j0;
#pragma unroll
    for (int q = 0; q < 4; ++q) {
      float4 o; o.x = acc[q * 4 + 0][v]; o.y = acc[q * 4 + 1][v];
                o.z = acc[q * 4 + 2][v]; o.w = acc[q * 4 + 3][v];
      *reinterpret_cast<float4*>(dst + q * 4) = o;
    }
  }
}

extern "C" void kernel_launch(void* const* d_in, const int* in_sizes, int n_in,
                              void* d_out, int out_size, void* d_ws, size_t ws_size,
                              hipStream_t stream) {
  const float* x = (const float*)d_in[0];
  const float* L = (const float*)d_in[1];
  const float* R = (const float*)d_in[2];
  float* out = (float*)d_out;

  ushort* Lt = (ushort*)d_ws;
  ushort* Rt = Lt + 2097152;
  ushort* T3 = Rt + 2097152;
  const size_t lr_bytes = (size_t)2 * 2097152 * 2;
  size_t avail = ws_size > lr_bytes ? ws_size - lr_bytes : 0;
  // Chunk rows so the T3 round-trip stays L3-resident (chunk working set:
  // x 64MB + T3 32MB + out 64MB = 160MB < 256MB Infinity Cache).
  long long rpc = 1024;
  long long fit = (long long)(avail / ((size_t)NCOL * 2));
  if (rpc > fit) rpc = fit;
  if (rpc > ROWS_TOTAL) rpc = ROWS_TOTAL;
  rpc &= ~15LL;
  if (rpc < 16) rpc = 16;

  k_prep<<<2048, 256, 0, stream>>>(L, R, Lt, Rt);

  for (long long row0 = 0; row0 < ROWS_TOTAL; row0 += rpc) {
    long long rows = (ROWS_TOTAL - row0 < rpc) ? (ROWS_TOTAL - row0) : rpc;
    int rowtiles = (int)(rows / 16);
    k_stage1<<<dim3(rowtiles * 16), 256, 0, stream>>>(x + row0 * NCOL, Lt, T3, rowtiles);
    k_stage2<<<dim3(rowtiles * 8), 512, 0, stream>>>(T3, Rt, out + row0 * NCOL, rowtiles);
  }
}

// Round 17
// 325.734 us; speedup vs baseline: 1.1193x; 1.0019x over previous
//
#include <hip/hip_runtime.h>
#include <hip/hip_bf16.h>

#define SDIM 128
#define NCOL 16384          // SDIM*SDIM
#define ROWS_TOTAL 4096
#define CHUNK 1024          // rows per chunk
#define RT_PC 64            // row-tiles per chunk
#define NCHUNK 4

using bf16x8 = __attribute__((ext_vector_type(8))) __bf16;
using su8    = __attribute__((ext_vector_type(8))) ushort;
using f32x4  = __attribute__((ext_vector_type(4))) float;

__device__ __forceinline__ ushort f2bf(float f) {
  __hip_bfloat16 h = __float2bfloat16(f);
  union { __hip_bfloat16 h; ushort u; } c; c.h = h;
  return c.u;
}

// ---- prep: L,R f32 -> bf16 in fragment-major layout ----
__global__ __launch_bounds__(256) void k_prep(const float* __restrict__ L,
                                              const float* __restrict__ R,
                                              ushort* __restrict__ Lt,
                                              ushort* __restrict__ Rt) {
  int id = blockIdx.x * 256 + threadIdx.x;
  const float* in = (id < 262144) ? L : R;
  ushort* outp    = (id < 262144) ? Lt : Rt;
  int t  = id & 262143;
  int t1 = t >> 11;
  int ks = (t >> 9) & 3;
  int tb = (t >> 6) & 7;
  int g  = (t >> 4) & 3;
  int tl = t & 15;
  const float* src = in + (size_t)(t1 * 128 + tb * 16 + tl) * 128 + ks * 32 + g * 8;
  float4 a = *reinterpret_cast<const float4*>(src);
  float4 b = *reinterpret_cast<const float4*>(src + 4);
  su8 o;
  o[0] = f2bf(a.x); o[1] = f2bf(a.y); o[2] = f2bf(a.z); o[3] = f2bf(a.w);
  o[4] = f2bf(b.x); o[5] = f2bf(b.y); o[6] = f2bf(b.z); o[7] = f2bf(b.w);
  *reinterpret_cast<su8*>(outp + (size_t)t * 8) = o;
}

// ======== stage1 body: 512 thr, block = 16 rows x 16 m (mg2 = brole&7) ========
// XCD = brole%8 = mg2 -> Lt slice 512 KB/XCD L2-resident; each 64B x line
// (16 m for one (r,k)) belongs to exactly one block.
__device__ __forceinline__ void s1_body(const float* __restrict__ x,
                                        const ushort* __restrict__ Lt,
                                        ushort* __restrict__ T3,
                                        int brole, ushort* sh, int tid) {
  int mg2 = brole & 7;
  int rt  = brole >> 3;            // 0..63
  int row0 = rt * 16;
  int m0 = mg2 * 16;

  // ---- stage x slice [16m][16r][128k] into LDS (f32->bf16), swizzled on r ----
  {
    int r = tid >> 5, kq = tid & 31;
    int k = kq << 2;
    const float4* p4 = reinterpret_cast<const float4*>(
        x + (size_t)(row0 + r) * NCOL + (size_t)k * SDIM + m0);
    ushort vv[4][16];
#pragma unroll
    for (int kk = 0; kk < 4; ++kk) {
#pragma unroll
      for (int q = 0; q < 4; ++q) {
        float4 a = p4[kk * 32 + q];
        vv[kk][q * 4 + 0] = f2bf(a.x); vv[kk][q * 4 + 1] = f2bf(a.y);
        vv[kk][q * 4 + 2] = f2bf(a.z); vv[kk][q * 4 + 3] = f2bf(a.w);
      }
    }
#pragma unroll
    for (int mloc = 0; mloc < 16; ++mloc) {
      int e = ((mloc * 16 + r) << 7) + k;
      int idx = e ^ ((r & 7) << 3);
      ushort4 w; w.x = vv[0][mloc]; w.y = vv[1][mloc];
                 w.z = vv[2][mloc]; w.w = vv[3][mloc];
      *reinterpret_cast<ushort4*>(&sh[idx]) = w;
    }
  }
  __syncthreads();

  int wave = tid >> 6, lane = tid & 63;
  int l15 = lane & 15, g = lane >> 4;
  int swz = (l15 & 7) << 3;
  int w4 = wave & 3, mgh = wave >> 2;      // j-quadrant, m-half
  int m0h = m0 + mgh * 8;
  const ushort* Lp = Lt + ((size_t)m0h * 32 + (size_t)w4 * 2) * 512 + (size_t)lane * 8;

  f32x4 st[2][8];
#pragma unroll
  for (int m = 0; m < 8; ++m) {
    int mloc = mgh * 8 + m;
    bf16x8 xf[4];
#pragma unroll
    for (int ks = 0; ks < 4; ++ks) {
      int e = ((mloc * 16 + l15) << 7) + ks * 32 + g * 8;
      xf[ks] = *reinterpret_cast<const bf16x8*>(&sh[e ^ swz]);
    }
    f32x4 a0 = {0.f, 0.f, 0.f, 0.f};
    f32x4 a1 = {0.f, 0.f, 0.f, 0.f};
#pragma unroll
    for (int ks = 0; ks < 4; ++ks) {
      bf16x8 l0 = *reinterpret_cast<const bf16x8*>(Lp + (size_t)((m * 4 + ks) * 8 + 0) * 512);
      bf16x8 l1 = *reinterpret_cast<const bf16x8*>(Lp + (size_t)((m * 4 + ks) * 8 + 1) * 512);
      a0 = __builtin_amdgcn_mfma_f32_16x16x32_bf16(xf[ks], l0, a0, 0, 0, 0);
      a1 = __builtin_amdgcn_mfma_f32_16x16x32_bf16(xf[ks], l1, a1, 0, 0, 0);
    }
    st[0][m] = a0;
    st[1][m] = a1;
  }

  int mg = mg2 * 2 + mgh;                  // global 8-m group 0..15
  int ks1 = mg >> 2, g2 = mg & 3;
#pragma unroll
  for (int jt = 0; jt < 2; ++jt) {
    int j = w4 * 32 + jt * 16 + l15;
#pragma unroll
    for (int v = 0; v < 4; ++v) {
      int rr = g * 4 + v;
      su8 o;
      o[0] = f2bf(st[jt][0][v]); o[1] = f2bf(st[jt][1][v]);
      o[2] = f2bf(st[jt][2][v]); o[3] = f2bf(st[jt][3][v]);
      o[4] = f2bf(st[jt][4][v]); o[5] = f2bf(st[jt][5][v]);
      o[6] = f2bf(st[jt][6][v]); o[7] = f2bf(st[jt][7][v]);
      size_t a = (((size_t)(rt * 128 + j) * 4 + ks1) * 64 + g2 * 16 + rr) * 8;
      *reinterpret_cast<su8*>(T3 + a) = o;
    }
  }
}

// ======== stage2 body: 512 thr (R16-validated), jg = brole&7 pinned to XCD ========
__device__ __forceinline__ void s2_body(const ushort* __restrict__ T3,
                                        const ushort* __restrict__ Rt,
                                        float* __restrict__ out,
                                        int brole, ushort* sh, int tid) {
  int jg = brole & 7;
  int rt = brole >> 3;
  int row0 = rt * 16;
  int j0 = jg * 16;

  int wave = tid >> 6, lane = tid & 63;
  int l15 = lane & 15, g = lane >> 4;
  int ibase = wave * 16;

  {
    const su8* s8 = reinterpret_cast<const su8*>(T3 + (size_t)(rt * 128 + j0) * 4 * 512);
    su8* d8 = reinterpret_cast<su8*>(sh);
#pragma unroll
    for (int q = 0; q < 8; ++q)
      d8[q * 512 + tid] = s8[q * 512 + tid];
  }
  __syncthreads();

  f32x4 acc[16];
#pragma unroll
  for (int jj = 0; jj < 16; ++jj) acc[jj] = {0.f, 0.f, 0.f, 0.f};

  const ushort* Rp = Rt + ((size_t)j0 * 32 + wave) * 512 + (size_t)lane * 8;
  const ushort* tp = sh + (size_t)lane * 8;

#pragma unroll
  for (int jj = 0; jj < 16; ++jj) {
#pragma unroll
    for (int ks = 0; ks < 4; ++ks) {
      bf16x8 af = *reinterpret_cast<const bf16x8*>(tp + (size_t)(jj * 4 + ks) * 512);
      bf16x8 bf = *reinterpret_cast<const bf16x8*>(Rp + (size_t)(jj * 32 + ks * 8) * 512);
      acc[jj] = __builtin_amdgcn_mfma_f32_16x16x32_bf16(af, bf, acc[jj], 0, 0, 0);
    }
  }

#pragma unroll
  for (int v = 0; v < 4; ++v) {
    float* dst = out + (size_t)(row0 + g * 4 + v) * NCOL + (size_t)(ibase + l15) * SDIM + j0;
#pragma unroll
    for (int q = 0; q < 4; ++q) {
      float4 o; o.x = acc[q * 4 + 0][v]; o.y = acc[q * 4 + 1][v];
                o.z = acc[q * 4 + 2][v]; o.w = acc[q * 4 + 3][v];
      *reinterpret_cast<float4*>(dst + q * 4) = o;
    }
  }
}

// ---- single-role kernels (grid 512) ----
__global__ __launch_bounds__(512, 4) void k_s1(const float* __restrict__ x,
                                               const ushort* __restrict__ Lt,
                                               ushort* __restrict__ T3) {
  __shared__ __align__(16) ushort sh[32768];
  s1_body(x, Lt, T3, blockIdx.x, sh, threadIdx.x);
}

__global__ __launch_bounds__(512, 4) void k_s2(const ushort* __restrict__ T3,
                                               const ushort* __restrict__ Rt,
                                               float* __restrict__ out) {
  __shared__ __align__(16) ushort sh[32768];
  s2_body(T3, Rt, out, blockIdx.x, sh, threadIdx.x);
}

// ---- merged kernel (grid 1024): blocks 0-511 = s2(chunk c), 512-1023 = s1(chunk c+1)
// Roles are fully independent (separate T3 buffers) -> no intra-kernel ordering needed.
__global__ __launch_bounds__(512, 4) void k_merge(const float* __restrict__ x_next,
                                                  const ushort* __restrict__ Lt,
                                                  const ushort* __restrict__ T3r,
                                                  ushort* __restrict__ T3w,
                                                  const ushort* __restrict__ Rt,
                                                  float* __restrict__ out_cur) {
  __shared__ __align__(16) ushort sh[32768];
  unsigned bid = blockIdx.x;
  if (bid < 512) s2_body(T3r, Rt, out_cur, bid, sh, threadIdx.x);
  else           s1_body(x_next, Lt, T3w, bid - 512, sh, threadIdx.x);
}

extern "C" void kernel_launch(void* const* d_in, const int* in_sizes, int n_in,
                              void* d_out, int out_size, void* d_ws, size_t ws_size,
                              hipStream_t stream) {
  const float* x = (const float*)d_in[0];
  const float* L = (const float*)d_in[1];
  const float* R = (const float*)d_in[2];
  float* out = (float*)d_out;

  ushort* Lt = (ushort*)d_ws;
  ushort* Rt = Lt + 2097152;
  ushort* T3a = Rt + 2097152;                       // 32 MB
  ushort* T3b = T3a + (size_t)CHUNK * NCOL;         // 32 MB
  const size_t need_db = (size_t)(8 + 64) * 1024 * 1024;  // Lt/Rt + 2 T3 buffers

  k_prep<<<2048, 256, 0, stream>>>(L, R, Lt, Rt);

  if (ws_size >= need_db) {
    // pipelined: s1(0) | s2(0)+s1(1) | s2(1)+s1(2) | s2(2)+s1(3) | s2(3)
    ushort* buf[2] = {T3a, T3b};
    k_s1<<<dim3(512), 512, 0, stream>>>(x, Lt, buf[0]);
    for (int c = 0; c < NCHUNK - 1; ++c) {
      k_merge<<<dim3(1024), 512, 0, stream>>>(x + (size_t)(c + 1) * CHUNK * NCOL,
                                              Lt, buf[c & 1], buf[(c + 1) & 1], Rt,
                                              out + (size_t)c * CHUNK * NCOL);
    }
    k_s2<<<dim3(512), 512, 0, stream>>>(buf[(NCHUNK - 1) & 1], Rt,
                                        out + (size_t)(NCHUNK - 1) * CHUNK * NCOL);
  } else {
    // fallback: serial, single T3 buffer
    for (int c = 0; c < NCHUNK; ++c) {
      k_s1<<<dim3(512), 512, 0, stream>>>(x + (size_t)c * CHUNK * NCOL, Lt, T3a);
      k_s2<<<dim3(512), 512, 0, stream>>>(T3a, Rt, out + (size_t)c * CHUNK * NCOL);
    }
  }
}